// Round 1
// baseline (92.185 us; speedup 1.0000x reference)
//
#include <hip/hip_runtime.h>
#include <hip/hip_bf16.h>

// FeatureEmbedding: out[b, f+1, e] = sum_d relu(x[b,f]*W1[f,d]+b1[f,d]) * W2[f,d,e] + b2[f,e]
//                   out[b, 0,   e] = cls_token[e]
// B=4096, F=64, D=256. Output f32 [4096][65][256].

#define B_  4096
#define F_  64
#define D_  256
#define ORS (65 * 256)   // out row stride (floats)

using f32x4  = __attribute__((ext_vector_type(4))) float;
using s16x8  = __attribute__((ext_vector_type(8))) short;

__device__ __forceinline__ unsigned short to_bf16_bits(float v) {
    __hip_bfloat16 h = __float2bfloat16(v);
    return *reinterpret_cast<unsigned short*>(&h);
}

// Main kernel: one block = one (feature, 128-row tile). 256 threads = 4 waves (2x2).
// Wave tile: 64 rows x 128 cols. MFMA 16x16x32 bf16, swapped operands -> D^T so
// each lane's float4 holds 4 consecutive output columns (dwordx4 stores).
__global__ __launch_bounds__(256, 2) void femb_main(
    const float* __restrict__ x,  const float* __restrict__ W1,
    const float* __restrict__ b1, const float* __restrict__ W2,
    const float* __restrict__ b2, float* __restrict__ out)
{
    __shared__ float w1s[D_];
    __shared__ float b1s[D_];
    __shared__ float xs[128];
    // W2 K-tile, transposed [n][k], row stride 72 bf16 = 144 B = 36 banks
    // -> b128 reads/writes land 8 lanes per 4-bank slot (optimal).
    __shared__ __align__(16) unsigned short bW[256][72];

    const int tid  = threadIdx.x;
    const int bid  = blockIdx.x;
    const int f    = bid & 63;        // same-f blocks share bid%8 -> same XCD (L2 reuse of W2_f)
    const int row0 = (bid >> 6) << 7; // 32 row tiles of 128

    // Stage per-feature vectors + x rows (one-time)
    w1s[tid] = W1[f * D_ + tid];
    b1s[tid] = b1[f * D_ + tid];
    if (tid < 128) xs[tid] = x[(size_t)(row0 + tid) * F_ + f];

    const int lane = tid & 63;
    const int wid  = tid >> 6;
    const int wm   = wid >> 1;   // 0..1 (row half)
    const int wn   = wid & 1;    // 0..1 (col half)
    const int llo  = lane & 15;
    const int lhi  = lane >> 4;

    __syncthreads();

    float xv[4];
    #pragma unroll
    for (int mt = 0; mt < 4; ++mt) xv[mt] = xs[wm * 64 + mt * 16 + llo];

    f32x4 acc[4][8];
    #pragma unroll
    for (int mt = 0; mt < 4; ++mt)
        #pragma unroll
        for (int nt = 0; nt < 8; ++nt)
            acc[mt][nt] = (f32x4){0.f, 0.f, 0.f, 0.f};

    // Thread t owns output column n = t for staging: loads W2[k][n] strided
    // (coalesced across the wave), writes contiguous bf16 row bW[n][k0..k0+63].
    const float* w2col = W2 + (size_t)f * D_ * D_ + tid;

    for (int kb = 0; kb < 4; ++kb) {
        // (1) issue all 64 strided global loads (independent, overlap barrier)
        float r[64];
        const float* p = w2col + (size_t)(kb * 64) * D_;
        #pragma unroll
        for (int j = 0; j < 64; ++j) r[j] = p[(size_t)j * D_];

        // (2) previous tile fully consumed
        __syncthreads();

        // (3) convert + transpose-write: one ds_write_b128 per 8 k
        #pragma unroll
        for (int j8 = 0; j8 < 8; ++j8) {
            union { s16x8 s; unsigned short u[8]; } pk;
            #pragma unroll
            for (int e = 0; e < 8; ++e)
                pk.u[e] = to_bf16_bits(r[j8 * 8 + e]);
            *reinterpret_cast<s16x8*>(&bW[tid][j8 * 8]) = pk.s;
        }
        __syncthreads();

        // (4) two K=32 MFMA substeps
        #pragma unroll
        for (int ks = 0; ks < 2; ++ks) {
            const int kg = kb * 64 + ks * 32 + lhi * 8; // global k of this lane's 8 elems
            float w1r[8], b1r[8];
            #pragma unroll
            for (int e = 0; e < 8; ++e) { w1r[e] = w1s[kg + e]; b1r[e] = b1s[kg + e]; }

            // A fragments (H rows) computed in registers
            s16x8 afrag[4];
            #pragma unroll
            for (int mt = 0; mt < 4; ++mt) {
                union { s16x8 s; unsigned short u[8]; } pk;
                #pragma unroll
                for (int e = 0; e < 8; ++e) {
                    float h = fmaf(xv[mt], w1r[e], b1r[e]);
                    h = fmaxf(h, 0.f);
                    pk.u[e] = to_bf16_bits(h);
                }
                afrag[mt] = pk.s;
            }

            const int kl = ks * 32 + lhi * 8;
            #pragma unroll
            for (int nt = 0; nt < 8; ++nt) {
                s16x8 bfrag = *reinterpret_cast<const s16x8*>(
                    &bW[wn * 128 + nt * 16 + llo][kl]);
                #pragma unroll
                for (int mt = 0; mt < 4; ++mt)
                    acc[mt][nt] = __builtin_amdgcn_mfma_f32_16x16x32_bf16(
                        bfrag, afrag[mt], acc[mt][nt], 0, 0, 0);
            }
        }
    }

    // Epilogue: D^T layout -> lane holds rows (l>>4)*4+r = consecutive COLUMNS.
    // row = row0 + wm*64 + mt*16 + llo ; col = wn*128 + nt*16 + lhi*4 + r
    const float* b2f = b2 + f * D_;
    float* obase = out + (size_t)(row0 + wm * 64 + llo) * ORS
                       + (f + 1) * D_ + wn * 128 + lhi * 4;
    #pragma unroll
    for (int nt = 0; nt < 8; ++nt) {
        f32x4 bv = *reinterpret_cast<const f32x4*>(&b2f[wn * 128 + nt * 16 + lhi * 4]);
        #pragma unroll
        for (int mt = 0; mt < 4; ++mt) {
            f32x4 v = acc[mt][nt] + bv;
            *reinterpret_cast<f32x4*>(obase + (size_t)mt * 16 * ORS + nt * 16) = v;
        }
    }
}

// cls row: out[b][0][:] = cls_token
__global__ void femb_cls(const float* __restrict__ cls, float* __restrict__ out)
{
    int i = blockIdx.x * 256 + threadIdx.x;  // 0 .. 4096*64-1
    int b = i >> 6;
    int q = i & 63;
    f32x4 v = *reinterpret_cast<const f32x4*>(cls + q * 4);
    *reinterpret_cast<f32x4*>(out + (size_t)b * ORS + q * 4) = v;
}

extern "C" void kernel_launch(void* const* d_in, const int* in_sizes, int n_in,
                              void* d_out, int out_size, void* d_ws, size_t ws_size,
                              hipStream_t stream)
{
    const float* x   = (const float*)d_in[0];
    const float* W1  = (const float*)d_in[1];
    const float* b1  = (const float*)d_in[2];
    const float* W2  = (const float*)d_in[3];
    const float* b2  = (const float*)d_in[4];
    const float* cls = (const float*)d_in[5];
    float* out = (float*)d_out;

    femb_cls<<<(B_ * 64) / 256, 256, 0, stream>>>(cls, out);
    femb_main<<<F_ * (B_ / 128), 256, 0, stream>>>(x, W1, b1, W2, b2, out);
}

// Round 2
// 89.177 us; speedup vs baseline: 1.0337x; 1.0337x over previous
//
#include <hip/hip_runtime.h>
#include <hip/hip_bf16.h>

// FeatureEmbedding: out[b, f+1, e] = sum_d relu(x[b,f]*W1[f,d]+b1[f,d]) * W2[f,d,e] + b2[f,e]
//                   out[b, 0,   e] = cls_token[e]
// B=4096, F=64, D=256. Output f32 [4096][65][256].

#define B_  4096
#define F_  64
#define D_  256
#define ORS (65 * 256)   // out row stride (floats)

using f32x4  = __attribute__((ext_vector_type(4))) float;
using s16x8  = __attribute__((ext_vector_type(8))) short;
typedef unsigned int u32;

__device__ __forceinline__ unsigned short to_bf16_bits(float v) {
    __hip_bfloat16 h = __float2bfloat16(v);
    return *reinterpret_cast<unsigned short*>(&h);
}

__device__ __forceinline__ void gload_lds16(const void* g, void* l) {
    __builtin_amdgcn_global_load_lds(
        (const __attribute__((address_space(1))) u32*)g,
        (__attribute__((address_space(3))) u32*)l, 16, 0, 0);
}

// ---------------------------------------------------------------------------
// Prep: W2 f32 [f][k][e]  ->  W2s bf16, layout [f][kb][n=e][p] where each p is
// a 16B unit of 8 k-values, pre-swizzled p = j ^ (n&7)  (j = logical k-slot).
// A linear 32KB copy of one [f][kb] block into LDS then IS the swizzled tile.
// ---------------------------------------------------------------------------
__global__ __launch_bounds__(256) void femb_prep(
    const float* __restrict__ W2, unsigned short* __restrict__ W2s)
{
    const int blk = blockIdx.x;        // f*4 + kb
    const int f   = blk >> 2;
    const int kb  = blk & 3;
    const int t   = threadIdx.x;       // owns output column n = t

    const float* col = W2 + (size_t)f * D_ * D_ + (size_t)(kb * 64) * D_ + t;
    float r[64];
    #pragma unroll
    for (int j = 0; j < 64; ++j) r[j] = col[(size_t)j * D_];

    unsigned short* ob = W2s + (size_t)blk * 16384 + t * 64; // thread row: 128 B
    #pragma unroll
    for (int j8 = 0; j8 < 8; ++j8) {
        union { s16x8 s; unsigned short u[8]; } pk;
        #pragma unroll
        for (int e = 0; e < 8; ++e) pk.u[e] = to_bf16_bits(r[j8 * 8 + e]);
        *reinterpret_cast<s16x8*>(ob + ((j8 ^ (t & 7)) * 8)) = pk.s;
    }
}

// ---------------------------------------------------------------------------
// Main: one block = one (feature, 128-row tile). 256 threads = 4 waves (2x2).
// Wave tile 64x128. B-tiles staged via global_load_lds from pre-swizzled W2s.
// ---------------------------------------------------------------------------
__global__ __launch_bounds__(256, 2) void femb_main2(
    const float* __restrict__ x,  const float* __restrict__ W1,
    const float* __restrict__ b1, const unsigned short* __restrict__ W2s,
    const float* __restrict__ b2, float* __restrict__ out)
{
    __shared__ float w1s[D_];
    __shared__ float b1s[D_];
    __shared__ float xs[128];
    __shared__ __align__(16) unsigned short bW[16384]; // 32 KB: [n=256][64 k bf16], k-slots XOR-swizzled

    const int tid  = threadIdx.x;
    const int bid  = blockIdx.x;
    const int f    = bid & 63;        // same-f blocks -> same bid%8 -> same XCD (L2 reuse of W2s_f)
    const int row0 = (bid >> 6) << 7;

    w1s[tid] = W1[f * D_ + tid];
    b1s[tid] = b1[f * D_ + tid];
    if (tid < 128) xs[tid] = x[(size_t)(row0 + tid) * F_ + f];

    const int lane = tid & 63;
    const int wid  = tid >> 6;
    const int wm   = wid >> 1;   // row half
    const int wn   = wid & 1;    // col half
    const int llo  = lane & 15;
    const int lhi  = lane >> 4;

    __syncthreads();

    float xv[4];
    #pragma unroll
    for (int mt = 0; mt < 4; ++mt) xv[mt] = xs[wm * 64 + mt * 16 + llo];

    f32x4 acc[4][8];
    #pragma unroll
    for (int mt = 0; mt < 4; ++mt)
        #pragma unroll
        for (int nt = 0; nt < 8; ++nt)
            acc[mt][nt] = (f32x4){0.f, 0.f, 0.f, 0.f};

    const char* gsrc = (const char*)(W2s + (size_t)f * 65536); // 4 kb-tiles * 32 KB

    for (int kb = 0; kb < 4; ++kb) {
        __syncthreads();  // previous tile fully consumed (kb=0: no-op pairing)
        const char* gt = gsrc + kb * 32768;
        #pragma unroll
        for (int r = 0; r < 8; ++r)
            gload_lds16(gt + tid * 16 + r * 4096, (char*)bW + tid * 16 + r * 4096);
        __syncthreads();  // drains vmcnt -> tile visible

        #pragma unroll
        for (int ks = 0; ks < 2; ++ks) {
            const int kg = kb * 64 + ks * 32 + lhi * 8;
            float w1r[8], b1r[8];
            #pragma unroll
            for (int e = 0; e < 8; ++e) { w1r[e] = w1s[kg + e]; b1r[e] = b1s[kg + e]; }

            s16x8 afrag[4];
            #pragma unroll
            for (int mt = 0; mt < 4; ++mt) {
                union { s16x8 s; unsigned short u[8]; } pk;
                #pragma unroll
                for (int e = 0; e < 8; ++e) {
                    float h = fmaf(xv[mt], w1r[e], b1r[e]);
                    pk.u[e] = to_bf16_bits(fmaxf(h, 0.f));
                }
                afrag[mt] = pk.s;
            }

            // bfrag: n = wn*128 + nt*16 + llo, logical slot j = ks*4+lhi,
            // physical p = j ^ (n&7) = j ^ (llo&7)  (nt*16, wn*128 keep n&7 = llo&7)
            const int base16 = (wn * 128 + llo) * 64 + (((ks * 4 + lhi) ^ (llo & 7)) * 8);
            #pragma unroll
            for (int nt = 0; nt < 8; ++nt) {
                s16x8 bfrag = *reinterpret_cast<const s16x8*>(&bW[base16 + nt * 1024]);
                #pragma unroll
                for (int mt = 0; mt < 4; ++mt)
                    acc[mt][nt] = __builtin_amdgcn_mfma_f32_16x16x32_bf16(
                        bfrag, afrag[mt], acc[mt][nt], 0, 0, 0);
            }
        }
    }

    // Epilogue: D^T layout -> lane float4 = 4 consecutive output columns.
    const float* b2f = b2 + f * D_;
    float* obase = out + (size_t)(row0 + wm * 64 + llo) * ORS
                       + (f + 1) * D_ + wn * 128 + lhi * 4;
    #pragma unroll
    for (int nt = 0; nt < 8; ++nt) {
        f32x4 bv = *reinterpret_cast<const f32x4*>(&b2f[wn * 128 + nt * 16 + lhi * 4]);
        #pragma unroll
        for (int mt = 0; mt < 4; ++mt) {
            f32x4 v = acc[mt][nt] + bv;
            *reinterpret_cast<f32x4*>(obase + (size_t)mt * 16 * ORS + nt * 16) = v;
        }
    }
}

// ---------------------------------------------------------------------------
// Fallback main (round-1, proven): used only if ws_size is too small.
// ---------------------------------------------------------------------------
__global__ __launch_bounds__(256, 2) void femb_main_fb(
    const float* __restrict__ x,  const float* __restrict__ W1,
    const float* __restrict__ b1, const float* __restrict__ W2,
    const float* __restrict__ b2, float* __restrict__ out)
{
    __shared__ float w1s[D_];
    __shared__ float b1s[D_];
    __shared__ float xs[128];
    __shared__ __align__(16) unsigned short bW[256][72];

    const int tid  = threadIdx.x;
    const int bid  = blockIdx.x;
    const int f    = bid & 63;
    const int row0 = (bid >> 6) << 7;

    w1s[tid] = W1[f * D_ + tid];
    b1s[tid] = b1[f * D_ + tid];
    if (tid < 128) xs[tid] = x[(size_t)(row0 + tid) * F_ + f];

    const int lane = tid & 63;
    const int wid  = tid >> 6;
    const int wm   = wid >> 1;
    const int wn   = wid & 1;
    const int llo  = lane & 15;
    const int lhi  = lane >> 4;

    __syncthreads();

    float xv[4];
    #pragma unroll
    for (int mt = 0; mt < 4; ++mt) xv[mt] = xs[wm * 64 + mt * 16 + llo];

    f32x4 acc[4][8];
    #pragma unroll
    for (int mt = 0; mt < 4; ++mt)
        #pragma unroll
        for (int nt = 0; nt < 8; ++nt)
            acc[mt][nt] = (f32x4){0.f, 0.f, 0.f, 0.f};

    const float* w2col = W2 + (size_t)f * D_ * D_ + tid;

    for (int kb = 0; kb < 4; ++kb) {
        float r[64];
        const float* p = w2col + (size_t)(kb * 64) * D_;
        #pragma unroll
        for (int j = 0; j < 64; ++j) r[j] = p[(size_t)j * D_];

        __syncthreads();
        #pragma unroll
        for (int j8 = 0; j8 < 8; ++j8) {
            union { s16x8 s; unsigned short u[8]; } pk;
            #pragma unroll
            for (int e = 0; e < 8; ++e) pk.u[e] = to_bf16_bits(r[j8 * 8 + e]);
            *reinterpret_cast<s16x8*>(&bW[tid][j8 * 8]) = pk.s;
        }
        __syncthreads();

        #pragma unroll
        for (int ks = 0; ks < 2; ++ks) {
            const int kg = kb * 64 + ks * 32 + lhi * 8;
            float w1r[8], b1r[8];
            #pragma unroll
            for (int e = 0; e < 8; ++e) { w1r[e] = w1s[kg + e]; b1r[e] = b1s[kg + e]; }

            s16x8 afrag[4];
            #pragma unroll
            for (int mt = 0; mt < 4; ++mt) {
                union { s16x8 s; unsigned short u[8]; } pk;
                #pragma unroll
                for (int e = 0; e < 8; ++e) {
                    float h = fmaf(xv[mt], w1r[e], b1r[e]);
                    pk.u[e] = to_bf16_bits(fmaxf(h, 0.f));
                }
                afrag[mt] = pk.s;
            }

            const int kl = ks * 32 + lhi * 8;
            #pragma unroll
            for (int nt = 0; nt < 8; ++nt) {
                s16x8 bfrag = *reinterpret_cast<const s16x8*>(
                    &bW[wn * 128 + nt * 16 + llo][kl]);
                #pragma unroll
                for (int mt = 0; mt < 4; ++mt)
                    acc[mt][nt] = __builtin_amdgcn_mfma_f32_16x16x32_bf16(
                        bfrag, afrag[mt], acc[mt][nt], 0, 0, 0);
            }
        }
    }

    const float* b2f = b2 + f * D_;
    float* obase = out + (size_t)(row0 + wm * 64 + llo) * ORS
                       + (f + 1) * D_ + wn * 128 + lhi * 4;
    #pragma unroll
    for (int nt = 0; nt < 8; ++nt) {
        f32x4 bv = *reinterpret_cast<const f32x4*>(&b2f[wn * 128 + nt * 16 + lhi * 4]);
        #pragma unroll
        for (int mt = 0; mt < 4; ++mt) {
            f32x4 v = acc[mt][nt] + bv;
            *reinterpret_cast<f32x4*>(obase + (size_t)mt * 16 * ORS + nt * 16) = v;
        }
    }
}

// cls row: out[b][0][:] = cls_token
__global__ void femb_cls(const float* __restrict__ cls, float* __restrict__ out)
{
    int i = blockIdx.x * 256 + threadIdx.x;
    int b = i >> 6;
    int q = i & 63;
    f32x4 v = *reinterpret_cast<const f32x4*>(cls + q * 4);
    *reinterpret_cast<f32x4*>(out + (size_t)b * ORS + q * 4) = v;
}

extern "C" void kernel_launch(void* const* d_in, const int* in_sizes, int n_in,
                              void* d_out, int out_size, void* d_ws, size_t ws_size,
                              hipStream_t stream)
{
    const float* x   = (const float*)d_in[0];
    const float* W1  = (const float*)d_in[1];
    const float* b1  = (const float*)d_in[2];
    const float* W2  = (const float*)d_in[3];
    const float* b2  = (const float*)d_in[4];
    const float* cls = (const float*)d_in[5];
    float* out = (float*)d_out;

    femb_cls<<<(B_ * 64) / 256, 256, 0, stream>>>(cls, out);

    const size_t need = (size_t)F_ * 4 * 16384 * sizeof(unsigned short); // 8 MiB
    if (ws_size >= need) {
        unsigned short* W2s = (unsigned short*)d_ws;
        femb_prep<<<F_ * 4, 256, 0, stream>>>(W2, W2s);
        femb_main2<<<F_ * (B_ / 128), 256, 0, stream>>>(x, W1, b1, W2s, b2, out);
    } else {
        femb_main_fb<<<F_ * (B_ / 128), 256, 0, stream>>>(x, W1, b1, W2, b2, out);
    }
}